// Round 2
// baseline (2339.100 us; speedup 1.0000x reference)
//
#include <hip/hip_runtime.h>
#include <hip/hip_bf16.h>

typedef __hip_bfloat16 bf16;

__device__ __forceinline__ float b2f(bf16 v) { return __bfloat162float(v); }
__device__ __forceinline__ bf16  f2b(float v) { return __float2bfloat16(v); }

constexpr int Bn   = 8;
constexpr int CIN  = 384;
constexpr int RESn = 28;
constexpr int Nn   = 784;    // RES*RES
constexpr int HEADSn = 8;
constexpr int DHn  = 1024;

// -------------------------------------------------- dtype detector (1 thread)
// If inputs are bf16, the low 16 bits of each 32-bit word of x are genuine
// bf16 values (exponent in [112,132] for N(0,1) data). If inputs are f32,
// those bits are random mantissa -> ~8% plausible. Writes flag: 1 = bf16.
__global__ void k_detect(const unsigned* __restrict__ xw, int* __restrict__ flag)
{
    if (blockIdx.x == 0 && threadIdx.x == 0) {
        int cnt = 0;
        for (int i = 0; i < 256; ++i) {
            unsigned lo = xw[i] & 0xFFFFu;
            int e = (int)((lo >> 7) & 0xFF);
            if (e >= 112 && e <= 132) ++cnt;
        }
        *flag = (cnt >= 128) ? 1 : 0;
    }
}

// ------------------------------------------------ convert input tensor -> f32
__global__ void k_conv(const void* __restrict__ src, float* __restrict__ dst,
                       int n, const int* __restrict__ flag)
{
    int isb = *flag;
    int stride = gridDim.x * blockDim.x;
    for (int i = blockIdx.x * blockDim.x + threadIdx.x; i < n; i += stride)
        dst[i] = isb ? b2f(((const bf16*)src)[i]) : ((const float*)src)[i];
}

// ---------------------------------------------------------------- mixed bias
// mb[g,p] = sum_h W1[g,h]*ab[h,p] + b1[g]
__global__ void k_mixbias(const float* __restrict__ ab, const float* __restrict__ W1,
                          const float* __restrict__ b1, float* __restrict__ mb)
{
    int i = blockIdx.x * 256 + threadIdx.x;
    if (i >= HEADSn * Nn) return;
    int g = i / Nn, p = i % Nn;
    float acc = b1[g];
    for (int h = 0; h < 8; ++h) acc += W1[g * 8 + h] * ab[h * Nn + p];
    mb[g * Nn + p] = acc;
}

// ------------------------------------------------------- fused q/k/v proj+BN
__global__ __launch_bounds__(256) void k_proj(
    const float* __restrict__ x,
    const float* __restrict__ Wq, const float* __restrict__ bq, const float* __restrict__ qs, const float* __restrict__ qb,
    const float* __restrict__ Wk, const float* __restrict__ bk, const float* __restrict__ ks, const float* __restrict__ kb,
    const float* __restrict__ Wv, const float* __restrict__ bv, const float* __restrict__ vs, const float* __restrict__ vb,
    bf16* __restrict__ qbuf, bf16* __restrict__ kbuf, bf16* __restrict__ vbuf)
{
    const int bi  = blockIdx.z;
    const int co0 = blockIdx.x * 64;
    const int n0  = blockIdx.y * 64;
    const int tid = threadIdx.x;
    const int tx = tid % 16, ty = tid / 16;

    __shared__ float Wt[64][17];
    __shared__ float Xt[16][65];

    const float *Wrow, *bb_, *ss_, *sh_;
    int cbase, seg;
    if (co0 < 256)      { seg = 0; Wrow = Wq; bb_ = bq; ss_ = qs; sh_ = qb; cbase = 0;   }
    else if (co0 < 512) { seg = 1; Wrow = Wk; bb_ = bk; ss_ = ks; sh_ = kb; cbase = 256; }
    else                { seg = 2; Wrow = Wv; bb_ = bv; ss_ = vs; sh_ = vb; cbase = 512; }

    float acc[4][4] = {};
    for (int k0 = 0; k0 < CIN; k0 += 16) {
        for (int i = tid; i < 64 * 16; i += 256) {
            int r = i / 16, c = i % 16;
            Wt[r][c] = Wrow[(size_t)(co0 + r - cbase) * CIN + k0 + c];
        }
        for (int i = tid; i < 16 * 64; i += 256) {
            int r = i / 64, c = i % 64;
            int n = n0 + c;
            Xt[r][c] = (n < Nn) ? x[((size_t)bi * CIN + k0 + r) * Nn + n] : 0.f;
        }
        __syncthreads();
        for (int kk = 0; kk < 16; ++kk) {
            float a[4], bvv[4];
            for (int i = 0; i < 4; ++i) a[i] = Wt[ty * 4 + i][kk];
            for (int j = 0; j < 4; ++j) bvv[j] = Xt[kk][tx * 4 + j];
            for (int i = 0; i < 4; ++i)
                for (int j = 0; j < 4; ++j) acc[i][j] += a[i] * bvv[j];
        }
        __syncthreads();
    }
    for (int i = 0; i < 4; ++i) {
        int co = co0 + ty * 4 + i;
        int lc = co - cbase;
        float alpha = ss_[lc];
        float beta  = bb_[lc] * alpha + sh_[lc];
        for (int j = 0; j < 4; ++j) {
            int n = n0 + tx * 4 + j;
            if (n >= Nn) continue;
            float y = alpha * acc[i][j] + beta;
            if (seg == 0) {
                int h = lc >> 5, d = lc & 31;
                qbuf[(((size_t)bi * 8 + h) * Nn + n) * 32 + d] = f2b(y);
            } else if (seg == 1) {
                int h = lc >> 5, d = lc & 31;
                kbuf[(((size_t)bi * 8 + h) * Nn + n) * 32 + d] = f2b(y);
            } else {
                vbuf[((size_t)bi * Nn + n) * DHn + lc] = f2b(y);
            }
        }
    }
}

// ------------------------------- depthwise conv+BN, ADDS into obuf (o += vl)
__global__ __launch_bounds__(256) void k_dwconv_add(
    const bf16* __restrict__ vbuf, const float* __restrict__ Wvl,
    const float* __restrict__ bvl, const float* __restrict__ vls, const float* __restrict__ vlb,
    bf16* __restrict__ obuf)
{
    int c  = blockIdx.x * 256 + threadIdx.x;
    int n  = blockIdx.y;
    int bi = blockIdx.z;
    int h = n / RESn, w = n % RESn;
    float acc = 0.f;
    for (int dh = -1; dh <= 1; ++dh)
        for (int dw = -1; dw <= 1; ++dw) {
            int hh = h + dh, ww = w + dw;
            if (hh < 0 || hh >= RESn || ww < 0 || ww >= RESn) continue;
            float wv = Wvl[c * 9 + (dh + 1) * 3 + (dw + 1)];
            acc += wv * b2f(vbuf[((size_t)bi * Nn + hh * RESn + ww) * DHn + c]);
        }
    float s = vls[c];
    size_t o = ((size_t)bi * Nn + n) * DHn + c;
    float vl = s * (acc + bvl[c]) + vlb[c];
    obuf[o] = f2b(b2f(obuf[o]) + vl);
}

// ------------------------------------------- logits: qk for 8 heads, th1 mix
__global__ __launch_bounds__(256) void k_logits(
    const bf16* __restrict__ qbuf, const bf16* __restrict__ kbuf,
    const float* __restrict__ mb, const int* __restrict__ idxs,
    const float* __restrict__ W1,
    bf16* __restrict__ attn, int bi)
{
    const int m0 = blockIdx.x * 64;
    const int n0 = blockIdx.y * 32;
    const int tid = threadIdx.x;
    const int tx = tid & 63;        // m lane
    const int tyq = tid >> 6;       // n group 0..3

    __shared__ float Qt[32][33];
    __shared__ float Kt[64][33];
    __shared__ float w1s[64];
    __shared__ float mbs[HEADSn * Nn];

    if (tid < 64) w1s[tid] = W1[tid];
    for (int i = tid; i < HEADSn * Nn; i += 256) mbs[i] = mb[i];

    float acc[8][8] = {};
    for (int h = 0; h < 8; ++h) {
        __syncthreads();
        for (int i = tid; i < 32 * 32; i += 256) {
            int r = i >> 5, c = i & 31;
            int n = n0 + r;
            Qt[r][c] = (n < Nn) ? b2f(qbuf[(((size_t)bi * 8 + h) * Nn + n) * 32 + c]) : 0.f;
        }
        for (int i = tid; i < 64 * 32; i += 256) {
            int r = i >> 5, c = i & 31;
            int m = m0 + r;
            Kt[r][c] = (m < Nn) ? b2f(kbuf[(((size_t)bi * 8 + h) * Nn + m) * 32 + c]) : 0.f;
        }
        __syncthreads();
        float qk[8] = {};
        for (int c = 0; c < 32; ++c) {
            float kv = Kt[tx][c];
            for (int i = 0; i < 8; ++i) qk[i] += Qt[tyq * 8 + i][c] * kv;
        }
        for (int g = 0; g < 8; ++g) {
            float w = w1s[g * 8 + h];
            for (int i = 0; i < 8; ++i) acc[g][i] += w * qk[i];
        }
    }

    const float scale = 0.17677669529663687f; // 32^-0.5
    int m = m0 + tx;
    if (m < Nn) {
        for (int i = 0; i < 8; ++i) {
            int n = n0 + tyq * 8 + i;
            if (n >= Nn) continue;
            int id = idxs[(size_t)n * Nn + m];
            for (int g = 0; g < 8; ++g) {
                float v = scale * acc[g][i] + mbs[g * Nn + id];
                attn[((size_t)g * Nn + n) * Nn + m] = f2b(v);
            }
        }
    }
}

// --------------------------------------- softmax (per head) + th2 mix, in-place
__global__ __launch_bounds__(256) void k_softmax_mix(
    bf16* __restrict__ attn, const float* __restrict__ W2, const float* __restrict__ b2v)
{
    const int n = blockIdx.x;
    const int tid = threadIdx.x;
    __shared__ float red[256];
    __shared__ float mx[8], li[8];
    __shared__ float w2s[64], b2s[8];
    if (tid < 64) w2s[tid] = W2[tid];
    if (tid < 8)  b2s[tid] = b2v[tid];

    for (int h = 0; h < 8; ++h) {
        float m = -1e30f;
        const bf16* row = attn + ((size_t)h * Nn + n) * Nn;
        for (int mm = tid; mm < Nn; mm += 256) m = fmaxf(m, b2f(row[mm]));
        red[tid] = m; __syncthreads();
        for (int s = 128; s > 0; s >>= 1) {
            if (tid < s) red[tid] = fmaxf(red[tid], red[tid + s]);
            __syncthreads();
        }
        if (tid == 0) mx[h] = red[0];
        __syncthreads();
    }
    for (int h = 0; h < 8; ++h) {
        float s = 0.f;
        const bf16* row = attn + ((size_t)h * Nn + n) * Nn;
        float mh = mx[h];
        for (int mm = tid; mm < Nn; mm += 256) s += __expf(b2f(row[mm]) - mh);
        red[tid] = s; __syncthreads();
        for (int st = 128; st > 0; st >>= 1) {
            if (tid < st) red[tid] += red[tid + st];
            __syncthreads();
        }
        if (tid == 0) li[h] = 1.f / red[0];
        __syncthreads();
    }
    for (int mm = tid; mm < Nn; mm += 256) {
        float e[8];
        for (int h = 0; h < 8; ++h)
            e[h] = __expf(b2f(attn[((size_t)h * Nn + n) * Nn + mm]) - mx[h]) * li[h];
        float o[8];
        for (int g = 0; g < 8; ++g) {
            float a = b2s[g];
            for (int h = 0; h < 8; ++h) a += w2s[g * 8 + h] * e[h];
            o[g] = a;
        }
        for (int g = 0; g < 8; ++g)
            attn[((size_t)g * Nn + n) * Nn + mm] = f2b(o[g]);
    }
}

// ------------------------------------------------------------ PV per head
__global__ __launch_bounds__(256) void k_pv(
    const bf16* __restrict__ attn, const bf16* __restrict__ vbuf,
    bf16* __restrict__ obuf, int bi)
{
    const int g  = blockIdx.z;
    const int n0 = blockIdx.y * 64;
    const int d0 = blockIdx.x * 64;
    const int tid = threadIdx.x;
    const int tx = tid % 16, ty = tid / 16;

    __shared__ float At[64][17];
    __shared__ float Bt[16][65];

    float acc[4][4] = {};
    for (int m0 = 0; m0 < Nn; m0 += 16) {
        for (int i = tid; i < 64 * 16; i += 256) {
            int r = i / 16, c = i % 16;
            int n = n0 + r;
            At[r][c] = (n < Nn) ? b2f(attn[((size_t)g * Nn + n) * Nn + m0 + c]) : 0.f;
        }
        for (int i = tid; i < 16 * 64; i += 256) {
            int r = i / 64, c = i % 64;
            Bt[r][c] = b2f(vbuf[((size_t)bi * Nn + m0 + r) * DHn + g * 128 + d0 + c]);
        }
        __syncthreads();
        for (int kk = 0; kk < 16; ++kk) {
            float a[4], bvv[4];
            for (int i = 0; i < 4; ++i) a[i] = At[ty * 4 + i][kk];
            for (int j = 0; j < 4; ++j) bvv[j] = Bt[kk][tx * 4 + j];
            for (int i = 0; i < 4; ++i)
                for (int j = 0; j < 4; ++j) acc[i][j] += a[i] * bvv[j];
        }
        __syncthreads();
    }
    for (int i = 0; i < 4; ++i) {
        int n = n0 + ty * 4 + i;
        if (n >= Nn) continue;
        for (int j = 0; j < 4; ++j) {
            int d = d0 + tx * 4 + j;
            obuf[((size_t)bi * Nn + n) * DHn + g * 128 + d] = f2b(acc[i][j]);
        }
    }
}

// --------------------------------------------------- output projection + BN
__global__ __launch_bounds__(256) void k_outproj(
    const bf16* __restrict__ obuf,
    const float* __restrict__ Wp, const float* __restrict__ bp,
    const float* __restrict__ ps, const float* __restrict__ pb,
    void* __restrict__ outv, const int* __restrict__ flag)
{
    const int bi  = blockIdx.z;
    const int oc0 = blockIdx.x * 64;
    const int n0  = blockIdx.y * 64;
    const int tid = threadIdx.x;
    const int tx = tid % 16, ty = tid / 16;

    __shared__ float Wt[64][17];
    __shared__ float Ot[64][17];

    float acc[4][4] = {};
    for (int c0 = 0; c0 < DHn; c0 += 16) {
        for (int i = tid; i < 64 * 16; i += 256) {
            int r = i / 16, cc = i % 16;
            Wt[r][cc] = Wp[(size_t)(oc0 + r) * DHn + c0 + cc];
        }
        for (int i = tid; i < 64 * 16; i += 256) {
            int r = i / 16, cc = i % 16;
            int n = n0 + r;
            Ot[r][cc] = (n < Nn) ? b2f(obuf[((size_t)bi * Nn + n) * DHn + c0 + cc]) : 0.f;
        }
        __syncthreads();
        for (int kk = 0; kk < 16; ++kk) {
            float a[4], bvv[4];
            for (int i = 0; i < 4; ++i) a[i] = Wt[ty * 4 + i][kk];
            for (int j = 0; j < 4; ++j) bvv[j] = Ot[tx * 4 + j][kk];
            for (int i = 0; i < 4; ++i)
                for (int j = 0; j < 4; ++j) acc[i][j] += a[i] * bvv[j];
        }
        __syncthreads();
    }
    int isb = *flag;
    for (int i = 0; i < 4; ++i) {
        int oc = oc0 + ty * 4 + i;
        float al = ps[oc];
        float be = bp[oc] * al + pb[oc];
        for (int j = 0; j < 4; ++j) {
            int n = n0 + tx * 4 + j;
            if (n >= Nn) continue;
            float y = al * acc[i][j] + be;
            size_t idx = ((size_t)bi * CIN + oc) * Nn + n;
            if (isb) ((bf16*)outv)[idx] = f2b(y);
            else     ((float*)outv)[idx] = y;
        }
    }
}

extern "C" void kernel_launch(void* const* d_in, const int* in_sizes, int n_in,
                              void* d_out, int out_size, void* d_ws, size_t ws_size,
                              hipStream_t stream)
{
    char* ws = (char*)d_ws;
    auto align256 = [](size_t v) { return (v + 255) & ~(size_t)255; };

    // layout
    size_t off = 0;
    size_t off_flag = off;            off = align256(off + 4);
    size_t p_off[26];
    for (int i = 0; i < 26; ++i) { p_off[i] = off; off += (size_t)in_sizes[i] * 4; }
    off = align256(off);
    size_t off_q    = off; off = align256(off + (size_t)Bn * 8 * Nn * 32 * 2);
    size_t off_k    = off; off = align256(off + (size_t)Bn * 8 * Nn * 32 * 2);
    size_t off_v    = off; off = align256(off + (size_t)Bn * Nn * DHn * 2);
    size_t off_o    = off; off = align256(off + (size_t)Bn * Nn * DHn * 2);
    size_t off_attn = off; off = align256(off + (size_t)HEADSn * Nn * Nn * 2);
    size_t off_mb   = off; off = align256(off + (size_t)HEADSn * Nn * 4);

    if (off > ws_size) return; // diagnostic: ws too small -> zeros out -> absmax ~17.4

    int*   flag = (int*)(ws + off_flag);
    float* P[26];
    for (int i = 0; i < 26; ++i) P[i] = (float*)(ws + p_off[i]);
    bf16*  qbuf = (bf16*)(ws + off_q);
    bf16*  kbuf = (bf16*)(ws + off_k);
    bf16*  vbuf = (bf16*)(ws + off_v);
    bf16*  obuf = (bf16*)(ws + off_o);
    bf16*  attn = (bf16*)(ws + off_attn);
    float* mb   = (float*)(ws + off_mb);
    const int* idxs = (const int*)d_in[26];

    k_detect<<<1, 64, 0, stream>>>((const unsigned*)d_in[0], flag);
    for (int i = 0; i < 26; ++i) {
        int n = in_sizes[i];
        int blocks = (n + 255) / 256; if (blocks > 2048) blocks = 2048;
        k_conv<<<blocks, 256, 0, stream>>>(d_in[i], P[i], n, flag);
    }

    // param aliases (setup_inputs order)
    float *x = P[0], *Wq = P[1], *bq = P[2], *qs = P[3], *qb = P[4],
          *Wk = P[5], *bk = P[6], *ks = P[7], *kb = P[8],
          *Wv = P[9], *bv = P[10], *vs = P[11], *vb = P[12],
          *Wvl = P[13], *bvl = P[14], *vls = P[15], *vlb = P[16],
          *W1 = P[17], *b1 = P[18], *W2 = P[19], *b2v = P[20],
          *Wp = P[21], *bp = P[22], *ps = P[23], *pb = P[24], *ab = P[25];

    k_mixbias<<<dim3((HEADSn * Nn + 255) / 256), 256, 0, stream>>>(ab, W1, b1, mb);
    k_proj<<<dim3(24, 13, 8), 256, 0, stream>>>(x, Wq, bq, qs, qb, Wk, bk, ks, kb,
                                                Wv, bv, vs, vb, qbuf, kbuf, vbuf);

    for (int bi = 0; bi < Bn; ++bi) {
        k_logits<<<dim3(13, 25), 256, 0, stream>>>(qbuf, kbuf, mb, idxs, W1, attn, bi);
        k_softmax_mix<<<dim3(Nn), 256, 0, stream>>>(attn, W2, b2v);
        k_pv<<<dim3(2, 13, 8), 256, 0, stream>>>(attn, vbuf, obuf, bi);
    }

    k_dwconv_add<<<dim3(4, Nn, 8), 256, 0, stream>>>(vbuf, Wvl, bvl, vls, vlb, obuf);
    k_outproj<<<dim3(6, 13, 8), 256, 0, stream>>>(obuf, Wp, bp, ps, pb, d_out, flag);
}

// Round 3
// 670.925 us; speedup vs baseline: 3.4864x; 3.4864x over previous
//
#include <hip/hip_runtime.h>
#include <hip/hip_bf16.h>

typedef __hip_bfloat16 bf16;
typedef __attribute__((ext_vector_type(8))) short short8v;
typedef __attribute__((ext_vector_type(4))) float f32x4;

__device__ __forceinline__ float b2f(bf16 v){ return __bfloat162float(v); }
__device__ __forceinline__ bf16  f2b(float v){ return __float2bfloat16(v); }

constexpr int Bn = 8, CIN = 384, RESn = 28, Nn = 784, DHn = 1024;

// -------------------------------------------------- dtype detector (1 thread)
__global__ void k_detect(const unsigned* __restrict__ xw, int* __restrict__ flag)
{
    if (blockIdx.x == 0 && threadIdx.x == 0) {
        int cnt = 0;
        for (int i = 0; i < 256; ++i) {
            unsigned lo = xw[i] & 0xFFFFu;
            int e = (int)((lo >> 7) & 0xFF);
            if (e >= 112 && e <= 132) ++cnt;
        }
        *flag = (cnt >= 128) ? 1 : 0;
    }
}

// ---------------------------------------------- convert input tensor -> bf16
__global__ void k_convb(const void* __restrict__ src, bf16* __restrict__ dst,
                        int n, const int* __restrict__ flag)
{
    int isb = *flag;
    int stride = gridDim.x * blockDim.x;
    for (int i = blockIdx.x * blockDim.x + threadIdx.x; i < n; i += stride)
        dst[i] = isb ? ((const bf16*)src)[i] : f2b(((const float*)src)[i]);
}

// ---------------------------------------------------------------- mixed bias
// mb[g,p] = sum_h W1[g,h]*ab[h,p] + b1[g]   (f32 out)
__global__ void k_mixbias(const bf16* __restrict__ ab, const bf16* __restrict__ W1,
                          const bf16* __restrict__ b1, float* __restrict__ mb)
{
    int i = blockIdx.x * 256 + threadIdx.x;
    if (i >= 8 * Nn) return;
    int g = i / Nn, p = i % Nn;
    float acc = b2f(b1[g]);
    for (int h = 0; h < 8; ++h) acc += b2f(W1[g * 8 + h]) * b2f(ab[h * Nn + p]);
    mb[g * Nn + p] = acc;
}

// ------------------------------------------------------- fused q/k/v proj+BN
// q,k: [b][n][256] (h*32+d);  v: [b][n][1024]
__global__ __launch_bounds__(256) void k_proj(
    const bf16* __restrict__ x,
    const bf16* __restrict__ Wq, const bf16* __restrict__ bq, const bf16* __restrict__ qs, const bf16* __restrict__ qb,
    const bf16* __restrict__ Wk, const bf16* __restrict__ bk, const bf16* __restrict__ ks, const bf16* __restrict__ kb,
    const bf16* __restrict__ Wv, const bf16* __restrict__ bv, const bf16* __restrict__ vs, const bf16* __restrict__ vb,
    bf16* __restrict__ qbuf, bf16* __restrict__ kbuf, bf16* __restrict__ vbuf)
{
    const int bi  = blockIdx.z;
    const int co0 = blockIdx.x * 64;
    const int n0  = blockIdx.y * 64;
    const int tid = threadIdx.x;
    const int tx = tid % 16, ty = tid / 16;

    __shared__ float Wt[64][17];
    __shared__ float Xt[16][65];

    const bf16 *Wrow, *bb_, *ss_, *sh_;
    int cbase, seg;
    if (co0 < 256)      { seg = 0; Wrow = Wq; bb_ = bq; ss_ = qs; sh_ = qb; cbase = 0;   }
    else if (co0 < 512) { seg = 1; Wrow = Wk; bb_ = bk; ss_ = ks; sh_ = kb; cbase = 256; }
    else                { seg = 2; Wrow = Wv; bb_ = bv; ss_ = vs; sh_ = vb; cbase = 512; }

    float acc[4][4] = {};
    for (int k0 = 0; k0 < CIN; k0 += 16) {
        for (int i = tid; i < 64 * 16; i += 256) {
            int r = i / 16, c = i % 16;
            Wt[r][c] = b2f(Wrow[(size_t)(co0 + r - cbase) * CIN + k0 + c]);
        }
        for (int i = tid; i < 16 * 64; i += 256) {
            int r = i / 64, c = i % 64;
            int n = n0 + c;
            Xt[r][c] = (n < Nn) ? b2f(x[((size_t)bi * CIN + k0 + r) * Nn + n]) : 0.f;
        }
        __syncthreads();
        for (int kk = 0; kk < 16; ++kk) {
            float a[4], bvv[4];
            for (int i = 0; i < 4; ++i) a[i] = Wt[ty * 4 + i][kk];
            for (int j = 0; j < 4; ++j) bvv[j] = Xt[kk][tx * 4 + j];
            for (int i = 0; i < 4; ++i)
                for (int j = 0; j < 4; ++j) acc[i][j] += a[i] * bvv[j];
        }
        __syncthreads();
    }
    for (int i = 0; i < 4; ++i) {
        int co = co0 + ty * 4 + i;
        int lc = co - cbase;
        float alpha = b2f(ss_[lc]);
        float beta  = b2f(bb_[lc]) * alpha + b2f(sh_[lc]);
        for (int j = 0; j < 4; ++j) {
            int n = n0 + tx * 4 + j;
            if (n >= Nn) continue;
            float y = alpha * acc[i][j] + beta;
            if (seg == 0)      qbuf[((size_t)bi * Nn + n) * 256 + lc] = f2b(y);
            else if (seg == 1) kbuf[((size_t)bi * Nn + n) * 256 + lc] = f2b(y);
            else               vbuf[((size_t)bi * Nn + n) * DHn + lc] = f2b(y);
        }
    }
}

// ---------------------------------------------------- v transpose: [n][c] -> [c][n]
__global__ __launch_bounds__(256) void k_vt(const bf16* __restrict__ vbuf, bf16* __restrict__ vt)
{
    __shared__ bf16 t[32][33];
    int b = blockIdx.z, n0 = blockIdx.x * 32, c0 = blockIdx.y * 32;
    int tid = threadIdx.x;
    for (int i = tid; i < 1024; i += 256) {
        int r = i >> 5, c = i & 31;
        int n = n0 + r;
        t[r][c] = (n < Nn) ? vbuf[((size_t)b * Nn + n) * DHn + c0 + c] : f2b(0.f);
    }
    __syncthreads();
    for (int i = tid; i < 1024; i += 256) {
        int r = i >> 5, c = i & 31;
        int n = n0 + c;
        if (n < Nn) vt[((size_t)b * DHn + c0 + r) * Nn + n] = t[c][r];
    }
}

// ------------------------------------------ qmix[bloc][g][n][c] = scale*W1[g,c>>5]*q
__global__ void k_qmix(const bf16* __restrict__ qbuf, const bf16* __restrict__ W1,
                       bf16* __restrict__ qmix, int bi0)
{
    int n = blockIdx.x, zz = blockIdx.y;
    int bloc = zz >> 3, g = zz & 7, b = bi0 + bloc;
    int c = threadIdx.x;
    const float scale = 0.17677669529663687f;
    float w = b2f(W1[g * 8 + (c >> 5)]) * scale;
    qmix[((size_t)(bloc * 8 + g) * Nn + n) * 256 + c] =
        f2b(w * b2f(qbuf[((size_t)b * Nn + n) * 256 + c]));
}

// -------------------- frag-linear staging: 64 rows x 32 k of a K-contig matrix
// LDS layout (short8 units): [(tile=row>>4)*4 + kgrp][16 rows] -> lane-linear frag reads
__device__ __forceinline__ void stage64x32(const bf16* __restrict__ src,
    int row0, int row_lim, int k0, int k_lim, int ld, short* lds, int tid)
{
    int r = tid >> 2, q = tid & 3;
    int row = row0 + r;
    int k = k0 + q * 8;
    short8v v = {0,0,0,0,0,0,0,0};
    if (row < row_lim && k < k_lim)
        v = *(const short8v*)((const short*)src + (size_t)row * ld + k);
    ((short8v*)lds)[((r >> 4) * 4 + q) * 16 + (r & 15)] = v;
}

#define MFMA_CORE(NSTEPS_EXPR, STAGE_A, STAGE_B)                                   \
    f32x4 acc00 = {0.f,0.f,0.f,0.f}, acc01 = acc00, acc10 = acc00, acc11 = acc00;  \
    const int lane = tid & 63, wv = tid >> 6, wm = wv >> 1, wn = wv & 1;           \
    for (int k0 = 0; k0 < (NSTEPS_EXPR); k0 += 32) {                               \
        __syncthreads();                                                           \
        STAGE_A; STAGE_B;                                                          \
        __syncthreads();                                                           \
        const short8v* A8 = (const short8v*)ldsA;                                  \
        const short8v* B8 = (const short8v*)ldsB;                                  \
        short8v a0 = A8[(wm*2+0)*64 + lane], a1 = A8[(wm*2+1)*64 + lane];          \
        short8v b0 = B8[(wn*2+0)*64 + lane], b1 = B8[(wn*2+1)*64 + lane];          \
        acc00 = __builtin_amdgcn_mfma_f32_16x16x32_bf16(a0, b0, acc00, 0, 0, 0);   \
        acc01 = __builtin_amdgcn_mfma_f32_16x16x32_bf16(a0, b1, acc01, 0, 0, 0);   \
        acc10 = __builtin_amdgcn_mfma_f32_16x16x32_bf16(a1, b0, acc10, 0, 0, 0);   \
        acc11 = __builtin_amdgcn_mfma_f32_16x16x32_bf16(a1, b1, acc11, 0, 0, 0);   \
    }

// ---------------- logits: attn[bloc][g][n][m] = qmix[g]·k^T + mb[g][idx[n,m]]
__global__ __launch_bounds__(256) void k_logits_m(
    const bf16* __restrict__ qmix, const bf16* __restrict__ kbuf,
    const float* __restrict__ mb, const int* __restrict__ idxs,
    bf16* __restrict__ attn, int bi0)
{
    __shared__ short ldsA[2048], ldsB[2048];
    __shared__ float mbs[Nn];
    const int tid = threadIdx.x;
    const int m0 = blockIdx.x * 64, n0 = blockIdx.y * 64;
    const int z = blockIdx.z, g = z & 7, bloc = z >> 3, b = bi0 + bloc;
    const bf16* Aq = qmix + (size_t)(bloc * 8 + g) * Nn * 256;
    const bf16* Bk = kbuf + (size_t)b * Nn * 256;
    for (int i = tid; i < Nn; i += 256) mbs[i] = mb[g * Nn + i];

    MFMA_CORE(256,
        stage64x32(Aq, n0, Nn, k0, 256, 256, ldsA, tid),
        stage64x32(Bk, m0, Nn, k0, 256, 256, ldsB, tid))

    bf16* arow = attn + (size_t)(bloc * 8 + g) * Nn * Nn;
    const int qrow = lane >> 4, mloc = lane & 15;
    #define LOG_EP(ACC, i, j) { \
        int mcol = m0 + wn*32 + (j)*16 + mloc; \
        if (mcol < Nn) { \
            int nb = n0 + wm*32 + (i)*16 + qrow*4; \
            for (int r = 0; r < 4; ++r) { int n = nb + r; if (n < Nn) { \
                float vv = ACC[r] + mbs[idxs[(size_t)n * Nn + mcol]]; \
                arow[(size_t)n * Nn + mcol] = f2b(vv); } } } }
    LOG_EP(acc00, 0, 0) LOG_EP(acc01, 0, 1) LOG_EP(acc10, 1, 0) LOG_EP(acc11, 1, 1)
    #undef LOG_EP
}

// --------------------------------------- softmax (per head) + th2 mix, in-place
__global__ __launch_bounds__(256) void k_softmax_mix(
    bf16* __restrict__ attn_all, const bf16* __restrict__ W2, const bf16* __restrict__ b2v)
{
    const int n = blockIdx.x, bloc = blockIdx.y;
    const int tid = threadIdx.x;
    bf16* attn = attn_all + (size_t)bloc * 8 * Nn * Nn;
    __shared__ float red[256];
    __shared__ float mx[8], li[8];
    __shared__ float w2s[64], b2s[8];
    if (tid < 64) w2s[tid] = b2f(W2[tid]);
    if (tid < 8)  b2s[tid] = b2f(b2v[tid]);

    for (int h = 0; h < 8; ++h) {
        float m = -1e30f;
        const bf16* row = attn + ((size_t)h * Nn + n) * Nn;
        for (int mm = tid; mm < Nn; mm += 256) m = fmaxf(m, b2f(row[mm]));
        red[tid] = m; __syncthreads();
        for (int s = 128; s > 0; s >>= 1) {
            if (tid < s) red[tid] = fmaxf(red[tid], red[tid + s]);
            __syncthreads();
        }
        if (tid == 0) mx[h] = red[0];
        __syncthreads();
    }
    for (int h = 0; h < 8; ++h) {
        float s = 0.f;
        const bf16* row = attn + ((size_t)h * Nn + n) * Nn;
        float mh = mx[h];
        for (int mm = tid; mm < Nn; mm += 256) s += __expf(b2f(row[mm]) - mh);
        red[tid] = s; __syncthreads();
        for (int st = 128; st > 0; st >>= 1) {
            if (tid < st) red[tid] += red[tid + st];
            __syncthreads();
        }
        if (tid == 0) li[h] = 1.f / red[0];
        __syncthreads();
    }
    for (int mm = tid; mm < Nn; mm += 256) {
        float e[8];
        for (int h = 0; h < 8; ++h)
            e[h] = __expf(b2f(attn[((size_t)h * Nn + n) * Nn + mm]) - mx[h]) * li[h];
        float o[8];
        for (int g = 0; g < 8; ++g) {
            float a = b2s[g];
            for (int h = 0; h < 8; ++h) a += w2s[g * 8 + h] * e[h];
            o[g] = a;
        }
        for (int g = 0; g < 8; ++g)
            attn[((size_t)g * Nn + n) * Nn + mm] = f2b(o[g]);
    }
}

// ------------------------------------------------ PV: obuf[b][n][c] = attn · v
__global__ __launch_bounds__(256) void k_pv_m(
    const bf16* __restrict__ attn, const bf16* __restrict__ vt,
    bf16* __restrict__ obuf, int bi0)
{
    __shared__ short ldsA[2048], ldsB[2048];
    const int tid = threadIdx.x;
    const int d0 = blockIdx.x * 64, n0 = blockIdx.y * 64;
    const int z = blockIdx.z, g = z & 7, bloc = z >> 3, b = bi0 + bloc;
    const bf16* Ap = attn + (size_t)(bloc * 8 + g) * Nn * Nn;
    const bf16* Bv = vt + ((size_t)b * DHn + g * 128 + d0) * Nn;

    MFMA_CORE(Nn,
        stage64x32(Ap, n0, Nn, k0, Nn, Nn, ldsA, tid),
        stage64x32(Bv, 0, 64, k0, Nn, Nn, ldsB, tid))

    bf16* ob = obuf + (size_t)b * Nn * DHn + g * 128;
    const int qrow = lane >> 4, dloc = lane & 15;
    #define PV_EP(ACC, i, j) { \
        int dc = d0 + wn*32 + (j)*16 + dloc; \
        int nb = n0 + wm*32 + (i)*16 + qrow*4; \
        for (int r = 0; r < 4; ++r) { int n = nb + r; if (n < Nn) \
            ob[(size_t)n * DHn + dc] = f2b(ACC[r]); } }
    PV_EP(acc00, 0, 0) PV_EP(acc01, 0, 1) PV_EP(acc10, 1, 0) PV_EP(acc11, 1, 1)
    #undef PV_EP
}

// ------------------------------- depthwise conv+BN, ADDS into obuf (o += vl)
__global__ __launch_bounds__(256) void k_dwconv_add(
    const bf16* __restrict__ vbuf, const bf16* __restrict__ Wvl,
    const bf16* __restrict__ bvl, const bf16* __restrict__ vls, const bf16* __restrict__ vlb,
    bf16* __restrict__ obuf)
{
    int c  = blockIdx.x * 256 + threadIdx.x;
    int n  = blockIdx.y;
    int bi = blockIdx.z;
    int h = n / RESn, w = n % RESn;
    float acc = 0.f;
    for (int dh = -1; dh <= 1; ++dh)
        for (int dw = -1; dw <= 1; ++dw) {
            int hh = h + dh, ww = w + dw;
            if (hh < 0 || hh >= RESn || ww < 0 || ww >= RESn) continue;
            float wv = b2f(Wvl[c * 9 + (dh + 1) * 3 + (dw + 1)]);
            acc += wv * b2f(vbuf[((size_t)bi * Nn + hh * RESn + ww) * DHn + c]);
        }
    float s = b2f(vls[c]);
    size_t o = ((size_t)bi * Nn + n) * DHn + c;
    float vl = s * (acc + b2f(bvl[c])) + b2f(vlb[c]);
    obuf[o] = f2b(b2f(obuf[o]) + vl);
}

// --------------------------------------------- output projection + BN (MFMA)
__global__ __launch_bounds__(256) void k_outproj_m(
    const bf16* __restrict__ Wp, const bf16* __restrict__ obuf,
    const bf16* __restrict__ bp, const bf16* __restrict__ ps, const bf16* __restrict__ pb,
    void* __restrict__ outv, const int* __restrict__ flag)
{
    __shared__ short ldsA[2048], ldsB[2048];
    const int tid = threadIdx.x;
    const int n0 = blockIdx.x * 64, oc0 = blockIdx.y * 64;
    const int b = blockIdx.z;
    const bf16* Bo = obuf + (size_t)b * Nn * DHn;

    MFMA_CORE(DHn,
        stage64x32(Wp, oc0, 384, k0, DHn, DHn, ldsA, tid),
        stage64x32(Bo, n0, Nn, k0, DHn, DHn, ldsB, tid))

    const int isb = *flag;
    const int qrow = lane >> 4, nloc = lane & 15;
    #define OP_EP(ACC, i, j) { \
        int n = n0 + wn*32 + (j)*16 + nloc; \
        if (n < Nn) { \
            int ocb = oc0 + wm*32 + (i)*16 + qrow*4; \
            for (int r = 0; r < 4; ++r) { int oc = ocb + r; \
                float al = b2f(ps[oc]); \
                float be = b2f(bp[oc]) * al + b2f(pb[oc]); \
                float y = al * ACC[r] + be; \
                size_t idx = ((size_t)b * CIN + oc) * Nn + n; \
                if (isb) ((bf16*)outv)[idx] = f2b(y); \
                else     ((float*)outv)[idx] = y; } } }
    OP_EP(acc00, 0, 0) OP_EP(acc01, 0, 1) OP_EP(acc10, 1, 0) OP_EP(acc11, 1, 1)
    #undef OP_EP
}

extern "C" void kernel_launch(void* const* d_in, const int* in_sizes, int n_in,
                              void* d_out, int out_size, void* d_ws, size_t ws_size,
                              hipStream_t stream)
{
    char* ws = (char*)d_ws;
    auto align256 = [](size_t v) { return (v + 255) & ~(size_t)255; };

    size_t off = 0;
    size_t off_flag = off;            off = align256(off + 4);
    size_t p_off[26];
    for (int i = 0; i < 26; ++i) { p_off[i] = off; off = align256(off + (size_t)in_sizes[i] * 2); }
    size_t off_mb = off;   off = align256(off + (size_t)8 * Nn * 4);
    size_t off_q  = off;   off = align256(off + (size_t)Bn * Nn * 256 * 2);
    size_t off_k  = off;   off = align256(off + (size_t)Bn * Nn * 256 * 2);
    size_t off_v  = off;   off = align256(off + (size_t)Bn * Nn * DHn * 2);
    size_t off_vt = off;   off = align256(off + (size_t)Bn * Nn * DHn * 2);
    size_t off_o  = off;   off = align256(off + (size_t)Bn * Nn * DHn * 2);
    size_t base = off;

    const size_t attn_per_b = (size_t)8 * Nn * Nn * 2;
    const size_t qmix_per_b = (size_t)8 * Nn * 256 * 2;
    int GB = 0;
    const int cand[4] = {8, 4, 2, 1};
    for (int ci = 0; ci < 4; ++ci) {
        size_t need = base + (size_t)cand[ci] * (attn_per_b + qmix_per_b) + 512;
        if (need <= ws_size) { GB = cand[ci]; break; }
    }
    if (!GB) return; // ws too small -> zeros out (diagnostic absmax ~17.4)

    size_t off_qmix = base;
    size_t off_attn = align256(off_qmix + (size_t)GB * qmix_per_b);

    int*  flag = (int*)(ws + off_flag);
    bf16* Pb[26];
    for (int i = 0; i < 26; ++i) Pb[i] = (bf16*)(ws + p_off[i]);
    float* mb  = (float*)(ws + off_mb);
    bf16* qbuf = (bf16*)(ws + off_q);
    bf16* kbuf = (bf16*)(ws + off_k);
    bf16* vbuf = (bf16*)(ws + off_v);
    bf16* vt   = (bf16*)(ws + off_vt);
    bf16* obuf = (bf16*)(ws + off_o);
    bf16* qmix = (bf16*)(ws + off_qmix);
    bf16* attn = (bf16*)(ws + off_attn);
    const int* idxs = (const int*)d_in[26];

    k_detect<<<1, 64, 0, stream>>>((const unsigned*)d_in[0], flag);
    for (int i = 0; i < 26; ++i) {
        int n = in_sizes[i];
        int blocks = (n + 255) / 256; if (blocks > 1024) blocks = 1024;
        k_convb<<<blocks, 256, 0, stream>>>(d_in[i], Pb[i], n, flag);
    }

    bf16 *x = Pb[0], *Wq = Pb[1], *bq = Pb[2], *qs = Pb[3], *qb = Pb[4],
         *Wk = Pb[5], *bk = Pb[6], *ks = Pb[7], *kb = Pb[8],
         *Wv = Pb[9], *bv = Pb[10], *vs = Pb[11], *vb = Pb[12],
         *Wvl = Pb[13], *bvl = Pb[14], *vls = Pb[15], *vlb = Pb[16],
         *W1 = Pb[17], *b1 = Pb[18], *W2 = Pb[19], *b2v = Pb[20],
         *Wp = Pb[21], *bp = Pb[22], *ps = Pb[23], *pb = Pb[24], *ab = Pb[25];

    k_mixbias<<<dim3((8 * Nn + 255) / 256), 256, 0, stream>>>(ab, W1, b1, mb);
    k_proj<<<dim3(24, 13, 8), 256, 0, stream>>>(x, Wq, bq, qs, qb, Wk, bk, ks, kb,
                                                Wv, bv, vs, vb, qbuf, kbuf, vbuf);
    k_vt<<<dim3(25, 32, 8), 256, 0, stream>>>(vbuf, vt);

    for (int bi0 = 0; bi0 < Bn; bi0 += GB) {
        k_qmix<<<dim3(Nn, GB * 8), 256, 0, stream>>>(qbuf, W1, qmix, bi0);
        k_logits_m<<<dim3(13, 13, GB * 8), 256, 0, stream>>>(qmix, kbuf, mb, idxs, attn, bi0);
        k_softmax_mix<<<dim3(Nn, GB), 256, 0, stream>>>(attn, W2, b2v);
        k_pv_m<<<dim3(2, 13, GB * 8), 256, 0, stream>>>(attn, vt, obuf, bi0);
    }

    k_dwconv_add<<<dim3(4, Nn, 8), 256, 0, stream>>>(vbuf, Wvl, bvl, vls, vlb, obuf);
    k_outproj_m<<<dim3(13, 6, 8), 256, 0, stream>>>(Wp, obuf, bp, ps, pb, d_out, flag);
}

// Round 4
// 331.912 us; speedup vs baseline: 7.0473x; 2.0214x over previous
//
#include <hip/hip_runtime.h>
#include <hip/hip_bf16.h>

typedef __hip_bfloat16 bf16;
typedef __attribute__((ext_vector_type(8))) short short8v;
typedef __attribute__((ext_vector_type(4))) float f32x4;

__device__ __forceinline__ float b2f(bf16 v){ return __bfloat162float(v); }
__device__ __forceinline__ bf16  f2b(float v){ return __float2bfloat16(v); }
__device__ __forceinline__ float su2f(short s){
    unsigned short us = (unsigned short)s;
    return __bfloat162float(*reinterpret_cast<bf16*>(&us));
}
__device__ __forceinline__ short f2su(float f){
    bf16 b = __float2bfloat16(f);
    return *reinterpret_cast<short*>(&b);
}

constexpr int Bn = 8, CIN = 384, RESn = 28, Nn = 784, DHn = 1024;

// -------------------------------------------------- dtype detector (1 thread)
__global__ void k_detect(const unsigned* __restrict__ xw, int* __restrict__ flag)
{
    if (blockIdx.x == 0 && threadIdx.x == 0) {
        int cnt = 0;
        for (int i = 0; i < 256; ++i) {
            unsigned lo = xw[i] & 0xFFFFu;
            int e = (int)((lo >> 7) & 0xFF);
            if (e >= 112 && e <= 132) ++cnt;
        }
        *flag = (cnt >= 128) ? 1 : 0;
    }
}

// ------------------------------------- convert ALL input tensors -> bf16, 1 launch
struct ConvArgs { const void* src[26]; unsigned long long dstoff[26]; int n[26]; };
__global__ void k_convb_all(ConvArgs a, char* __restrict__ ws, const int* __restrict__ flag)
{
    int i = blockIdx.y;
    int n = a.n[i];
    const void* s = a.src[i];
    bf16* d = (bf16*)(ws + a.dstoff[i]);
    int isb = *flag;
    int stride = gridDim.x * blockDim.x;
    for (int t = blockIdx.x * blockDim.x + threadIdx.x; t < n; t += stride)
        d[t] = isb ? ((const bf16*)s)[t] : f2b(((const float*)s)[t]);
}

// ---------------------------------------------------------------- mixed bias
__global__ void k_mixbias(const bf16* __restrict__ ab, const bf16* __restrict__ W1,
                          const bf16* __restrict__ b1, float* __restrict__ mb)
{
    int i = blockIdx.x * 256 + threadIdx.x;
    if (i >= 8 * Nn) return;
    int g = i / Nn, p = i % Nn;
    float acc = b2f(b1[g]);
    for (int h = 0; h < 8; ++h) acc += b2f(W1[g * 8 + h]) * b2f(ab[h * Nn + p]);
    mb[g * Nn + p] = acc;
}

// ----------------------------------------- pack Wq|Wk|Wv -> Wqkv [1536][384]
__global__ void k_wpack(const bf16* __restrict__ Wq, const bf16* __restrict__ Wk,
                        const bf16* __restrict__ Wv, bf16* __restrict__ Wqkv)
{
    int t = blockIdx.x * 256 + threadIdx.x;   // short8 index
    if (t >= 1536 * 48) return;
    int co = t / 48, j = t % 48;
    const bf16* src = (co < 256) ? Wq + (size_t)co * 384
                    : (co < 512) ? Wk + (size_t)(co - 256) * 384
                                 : Wv + (size_t)(co - 512) * 384;
    ((short8v*)Wqkv)[t] = ((const short8v*)src)[j];
}

// ------------------------------------------------- affine (alpha,beta)[1536]
__global__ void k_affine(const bf16* bq, const bf16* qs, const bf16* qb,
                         const bf16* bk, const bf16* ks, const bf16* kb,
                         const bf16* bv, const bf16* vs, const bf16* vb,
                         float* __restrict__ al, float* __restrict__ be)
{
    int co = blockIdx.x * 256 + threadIdx.x;
    if (co >= 1536) return;
    const bf16 *b_, *s_, *h_; int lc;
    if (co < 256)      { b_ = bq; s_ = qs; h_ = qb; lc = co; }
    else if (co < 512) { b_ = bk; s_ = ks; h_ = kb; lc = co - 256; }
    else               { b_ = bv; s_ = vs; h_ = vb; lc = co - 512; }
    float a = b2f(s_[lc]);
    al[co] = a;
    be[co] = b2f(b_[lc]) * a + b2f(h_[lc]);
}

// --------------------------------- x transpose: [b][384][784] -> [b][784][384]
__global__ __launch_bounds__(256) void k_xt(const bf16* __restrict__ x, bf16* __restrict__ xt)
{
    __shared__ bf16 t[32][33];
    int b = blockIdx.z, n0 = blockIdx.x * 32, c0 = blockIdx.y * 32;
    int tid = threadIdx.x;
    for (int i = tid; i < 1024; i += 256) {
        int r = i >> 5, c = i & 31;
        int n = n0 + c;
        t[r][c] = (n < Nn) ? x[((size_t)b * CIN + c0 + r) * Nn + n] : f2b(0.f);
    }
    __syncthreads();
    for (int i = tid; i < 1024; i += 256) {
        int r = i >> 5, c = i & 31;
        int n = n0 + r;
        if (n < Nn) xt[((size_t)b * Nn + n) * CIN + c0 + c] = t[c][r];
    }
}

// ---------------------------------------------------- v transpose: [n][c] -> [c][n]
__global__ __launch_bounds__(256) void k_vt(const bf16* __restrict__ vbuf, bf16* __restrict__ vt)
{
    __shared__ bf16 t[32][33];
    int b = blockIdx.z, n0 = blockIdx.x * 32, c0 = blockIdx.y * 32;
    int tid = threadIdx.x;
    for (int i = tid; i < 1024; i += 256) {
        int r = i >> 5, c = i & 31;
        int n = n0 + r;
        t[r][c] = (n < Nn) ? vbuf[((size_t)b * Nn + n) * DHn + c0 + c] : f2b(0.f);
    }
    __syncthreads();
    for (int i = tid; i < 1024; i += 256) {
        int r = i >> 5, c = i & 31;
        int n = n0 + c;
        if (n < Nn) vt[((size_t)b * DHn + c0 + r) * Nn + n] = t[c][r];
    }
}

// -------------------- frag-linear staging: 64 rows x 32 k of a K-contig matrix
__device__ __forceinline__ void stage64x32(const bf16* __restrict__ src,
    int row0, int row_lim, int k0, int k_lim, int ld, short* lds, int tid)
{
    int r = tid >> 2, q = tid & 3;
    int row = row0 + r;
    int k = k0 + q * 8;
    short8v v = {0,0,0,0,0,0,0,0};
    if (row < row_lim && k < k_lim)
        v = *(const short8v*)((const short*)src + (size_t)row * ld + k);
    ((short8v*)lds)[((r >> 4) * 4 + q) * 16 + (r & 15)] = v;
}

// same, with a wave-uniform scale applied element-wise during staging
__device__ __forceinline__ void stage64x32s(const bf16* __restrict__ src,
    int row0, int row_lim, int k0, int ld, short* lds, int tid, float w)
{
    int r = tid >> 2, q = tid & 3;
    int row = row0 + r;
    int k = k0 + q * 8;
    short8v v = {0,0,0,0,0,0,0,0};
    if (row < row_lim)
        v = *(const short8v*)((const short*)src + (size_t)row * ld + k);
    short8v o;
    #pragma unroll
    for (int j = 0; j < 8; ++j) o[j] = f2su(su2f(v[j]) * w);
    ((short8v*)lds)[((r >> 4) * 4 + q) * 16 + (r & 15)] = o;
}

#define MFMA_CORE(NSTEPS_EXPR, STAGE_A, STAGE_B)                                   \
    f32x4 acc00 = {0.f,0.f,0.f,0.f}, acc01 = acc00, acc10 = acc00, acc11 = acc00;  \
    const int lane = tid & 63, wv = tid >> 6, wm = wv >> 1, wn = wv & 1;           \
    for (int k0 = 0; k0 < (NSTEPS_EXPR); k0 += 32) {                               \
        __syncthreads();                                                           \
        STAGE_A; STAGE_B;                                                          \
        __syncthreads();                                                           \
        const short8v* A8 = (const short8v*)ldsA;                                  \
        const short8v* B8 = (const short8v*)ldsB;                                  \
        short8v a0 = A8[(wm*2+0)*64 + lane], a1 = A8[(wm*2+1)*64 + lane];          \
        short8v b0 = B8[(wn*2+0)*64 + lane], b1 = B8[(wn*2+1)*64 + lane];          \
        acc00 = __builtin_amdgcn_mfma_f32_16x16x32_bf16(a0, b0, acc00, 0, 0, 0);   \
        acc01 = __builtin_amdgcn_mfma_f32_16x16x32_bf16(a0, b1, acc01, 0, 0, 0);   \
        acc10 = __builtin_amdgcn_mfma_f32_16x16x32_bf16(a1, b0, acc10, 0, 0, 0);   \
        acc11 = __builtin_amdgcn_mfma_f32_16x16x32_bf16(a1, b1, acc11, 0, 0, 0);   \
    }

// --------------------------------------------- q/k/v projection + BN (MFMA)
// C[n][co]: A = xt rows (n), B = Wqkv rows (co)
__global__ __launch_bounds__(256) void k_proj_m(
    const bf16* __restrict__ xt, const bf16* __restrict__ Wqkv,
    const float* __restrict__ al, const float* __restrict__ be,
    bf16* __restrict__ qbuf, bf16* __restrict__ kbuf, bf16* __restrict__ vbuf)
{
    __shared__ short ldsA[2048], ldsB[2048];
    const int tid = threadIdx.x;
    const int n0 = blockIdx.x * 64, co0 = blockIdx.y * 64;
    const int b = blockIdx.z;
    const bf16* Ax = xt + (size_t)b * Nn * CIN;

    MFMA_CORE(CIN,
        stage64x32(Ax, n0, Nn, k0, CIN, CIN, ldsA, tid),
        stage64x32(Wqkv, co0, 1536, k0, CIN, CIN, ldsB, tid))

    const int qrow = lane >> 4, cloc = lane & 15;
    #define PJ_EP(ACC, i, j) { \
        int co = co0 + wn*32 + (j)*16 + cloc; \
        float a_ = al[co], bb_ = be[co]; \
        int nb = n0 + wm*32 + (i)*16 + qrow*4; \
        for (int r = 0; r < 4; ++r) { int n = nb + r; if (n < Nn) { \
            float y = a_ * ACC[r] + bb_; \
            if (co < 256)      qbuf[((size_t)b*Nn+n)*256 + co]        = f2b(y); \
            else if (co < 512) kbuf[((size_t)b*Nn+n)*256 + (co-256)]  = f2b(y); \
            else               vbuf[((size_t)b*Nn+n)*DHn + (co-512)]  = f2b(y); } } }
    PJ_EP(acc00, 0, 0) PJ_EP(acc01, 0, 1) PJ_EP(acc10, 1, 0) PJ_EP(acc11, 1, 1)
    #undef PJ_EP
}

// ---------------- logits: attn[bloc][g][n][m] = (scaled,W1-mixed q)·k^T + mb[g][idx]
__global__ __launch_bounds__(256) void k_logits_m(
    const bf16* __restrict__ qbuf, const bf16* __restrict__ kbuf,
    const bf16* __restrict__ W1,
    const float* __restrict__ mb, const int* __restrict__ idxs,
    bf16* __restrict__ attn, int bi0)
{
    __shared__ short ldsA[2048], ldsB[2048];
    __shared__ float mbs[Nn];
    const int tid = threadIdx.x;
    const int m0 = blockIdx.x * 64, n0 = blockIdx.y * 64;
    const int z = blockIdx.z, g = z & 7, bloc = z >> 3, b = bi0 + bloc;
    const bf16* Aq = qbuf + (size_t)b * Nn * 256;
    const bf16* Bk = kbuf + (size_t)b * Nn * 256;
    for (int i = tid; i < Nn; i += 256) mbs[i] = mb[g * Nn + i];
    const float scale = 0.17677669529663687f;

    MFMA_CORE(256,
        stage64x32s(Aq, n0, Nn, k0, 256, ldsA, tid, scale * b2f(W1[g*8 + (k0>>5)])),
        stage64x32(Bk, m0, Nn, k0, 256, 256, ldsB, tid))

    bf16* arow = attn + (size_t)(bloc * 8 + g) * Nn * Nn;
    const int qrow = lane >> 4, mloc = lane & 15;
    #define LOG_EP(ACC, i, j) { \
        int mcol = m0 + wn*32 + (j)*16 + mloc; \
        if (mcol < Nn) { \
            int nb = n0 + wm*32 + (i)*16 + qrow*4; \
            for (int r = 0; r < 4; ++r) { int n = nb + r; if (n < Nn) { \
                float vv = ACC[r] + mbs[idxs[(size_t)n * Nn + mcol]]; \
                arow[(size_t)n * Nn + mcol] = f2b(vv); } } } }
    LOG_EP(acc00, 0, 0) LOG_EP(acc01, 0, 1) LOG_EP(acc10, 1, 0) LOG_EP(acc11, 1, 1)
    #undef LOG_EP
}

// ---------------- softmax (per head) + th2 mix, LDS row-cached, in-place
__global__ __launch_bounds__(256) void k_softmax_mix(
    bf16* __restrict__ attn_all, const bf16* __restrict__ W2, const bf16* __restrict__ b2v)
{
    const int n = blockIdx.x, bloc = blockIdx.y;
    bf16* attn = attn_all + (size_t)bloc * 8 * Nn * Nn;
    const int tid = threadIdx.x;
    const int grp = tid >> 5;      // head
    const int gl  = tid & 31;
    __shared__ float e[8][788];
    __shared__ float mxs[8], lis[8];
    __shared__ float w2s[64], b2s[8];
    if (tid < 64) w2s[tid] = b2f(W2[tid]);
    if (tid < 8)  b2s[tid] = b2f(b2v[tid]);

    const bf16* row = attn + ((size_t)grp * Nn + n) * Nn;
    float mloc = -1e30f;
    for (int j = gl; j < 98; j += 32) {          // 98 short8 per 784-row
        short8v v = ((const short8v*)row)[j];
        #pragma unroll
        for (int u = 0; u < 8; ++u) {
            float f = su2f(v[u]);
            e[grp][j * 8 + u] = f;
            mloc = fmaxf(mloc, f);
        }
    }
    #pragma unroll
    for (int s = 16; s > 0; s >>= 1) mloc = fmaxf(mloc, __shfl_xor(mloc, s, 64));
    if (gl == 0) mxs[grp] = mloc;
    __syncthreads();

    float mh = mxs[grp];
    float sloc = 0.f;
    for (int j = gl; j < 98; j += 32) {
        #pragma unroll
        for (int u = 0; u < 8; ++u) {
            float ev = __expf(e[grp][j * 8 + u] - mh);
            e[grp][j * 8 + u] = ev;
            sloc += ev;
        }
    }
    #pragma unroll
    for (int s = 16; s > 0; s >>= 1) sloc += __shfl_xor(sloc, s, 64);
    if (gl == 0) lis[grp] = 1.f / sloc;
    __syncthreads();

    float li[8];
    #pragma unroll
    for (int h = 0; h < 8; ++h) li[h] = lis[h];
    for (int m = tid; m < Nn; m += 256) {
        float eh[8];
        #pragma unroll
        for (int h = 0; h < 8; ++h) eh[h] = e[h][m] * li[h];
        #pragma unroll
        for (int g = 0; g < 8; ++g) {
            float a = b2s[g];
            #pragma unroll
            for (int h = 0; h < 8; ++h) a += w2s[g * 8 + h] * eh[h];
            attn[((size_t)g * Nn + n) * Nn + m] = f2b(a);
        }
    }
}

// ------------------------------------------------ PV: obuf[b][n][c] = attn · v
__global__ __launch_bounds__(256) void k_pv_m(
    const bf16* __restrict__ attn, const bf16* __restrict__ vt,
    bf16* __restrict__ obuf, int bi0)
{
    __shared__ short ldsA[2048], ldsB[2048];
    const int tid = threadIdx.x;
    const int d0 = blockIdx.x * 64, n0 = blockIdx.y * 64;
    const int z = blockIdx.z, g = z & 7, bloc = z >> 3, b = bi0 + bloc;
    const bf16* Ap = attn + (size_t)(bloc * 8 + g) * Nn * Nn;
    const bf16* Bv = vt + ((size_t)b * DHn + g * 128 + d0) * Nn;

    MFMA_CORE(Nn,
        stage64x32(Ap, n0, Nn, k0, Nn, Nn, ldsA, tid),
        stage64x32(Bv, 0, 64, k0, Nn, Nn, ldsB, tid))

    bf16* ob = obuf + (size_t)b * Nn * DHn + g * 128;
    const int qrow = lane >> 4, dloc = lane & 15;
    #define PV_EP(ACC, i, j) { \
        int dc = d0 + wn*32 + (j)*16 + dloc; \
        int nb = n0 + wm*32 + (i)*16 + qrow*4; \
        for (int r = 0; r < 4; ++r) { int n = nb + r; if (n < Nn) \
            ob[(size_t)n * DHn + dc] = f2b(ACC[r]); } }
    PV_EP(acc00, 0, 0) PV_EP(acc01, 0, 1) PV_EP(acc10, 1, 0) PV_EP(acc11, 1, 1)
    #undef PV_EP
}

// ------------------- depthwise conv+BN, ADDS into obuf (o += vl), vectorized
__global__ __launch_bounds__(256) void k_dwconv_add(
    const bf16* __restrict__ vbuf, const bf16* __restrict__ Wvl,
    const bf16* __restrict__ bvl, const bf16* __restrict__ vls, const bf16* __restrict__ vlb,
    bf16* __restrict__ obuf)
{
    const int t = threadIdx.x;
    const int n = blockIdx.y * 2 + (t >> 7);
    const int bi = blockIdx.z;
    const int c0 = (t & 127) * 8;
    const int h = n / RESn, w = n % RESn;
    float acc[8] = {};
    #pragma unroll
    for (int dh = -1; dh <= 1; ++dh)
        #pragma unroll
        for (int dw = -1; dw <= 1; ++dw) {
            int hh = h + dh, ww = w + dw;
            if (hh < 0 || hh >= RESn || ww < 0 || ww >= RESn) continue;
            short8v v = *(const short8v*)&vbuf[((size_t)bi * Nn + hh * RESn + ww) * DHn + c0];
            int widx = (dh + 1) * 3 + (dw + 1);
            #pragma unroll
            for (int u = 0; u < 8; ++u)
                acc[u] += b2f(Wvl[(size_t)(c0 + u) * 9 + widx]) * su2f(v[u]);
        }
    size_t off = ((size_t)bi * Nn + n) * DHn + c0;
    short8v ov = *(short8v*)&obuf[off];
    short8v res;
    #pragma unroll
    for (int u = 0; u < 8; ++u) {
        float s = b2f(vls[c0 + u]);
        float vl = s * (acc[u] + b2f(bvl[c0 + u])) + b2f(vlb[c0 + u]);
        res[u] = f2su(su2f(ov[u]) + vl);
    }
    *(short8v*)&obuf[off] = res;
}

// --------------------------------------------- output projection + BN (MFMA)
__global__ __launch_bounds__(256) void k_outproj_m(
    const bf16* __restrict__ Wp, const bf16* __restrict__ obuf,
    const bf16* __restrict__ bp, const bf16* __restrict__ ps, const bf16* __restrict__ pb,
    void* __restrict__ outv, const int* __restrict__ flag)
{
    __shared__ short ldsA[2048], ldsB[2048];
    const int tid = threadIdx.x;
    const int n0 = blockIdx.x * 64, oc0 = blockIdx.y * 64;
    const int b = blockIdx.z;
    const bf16* Bo = obuf + (size_t)b * Nn * DHn;

    MFMA_CORE(DHn,
        stage64x32(Wp, oc0, 384, k0, DHn, DHn, ldsA, tid),
        stage64x32(Bo, n0, Nn, k0, DHn, DHn, ldsB, tid))

    const int isb = *flag;
    const int qrow = lane >> 4, nloc = lane & 15;
    #define OP_EP(ACC, i, j) { \
        int n = n0 + wn*32 + (j)*16 + nloc; \
        if (n < Nn) { \
            int ocb = oc0 + wm*32 + (i)*16 + qrow*4; \
            for (int r = 0; r < 4; ++r) { int oc = ocb + r; \
                float al = b2f(ps[oc]); \
                float bee = b2f(bp[oc]) * al + b2f(pb[oc]); \
                float y = al * ACC[r] + bee; \
                size_t idx = ((size_t)b * CIN + oc) * Nn + n; \
                if (isb) ((bf16*)outv)[idx] = f2b(y); \
                else     ((float*)outv)[idx] = y; } } }
    OP_EP(acc00, 0, 0) OP_EP(acc01, 0, 1) OP_EP(acc10, 1, 0) OP_EP(acc11, 1, 1)
    #undef OP_EP
}

extern "C" void kernel_launch(void* const* d_in, const int* in_sizes, int n_in,
                              void* d_out, int out_size, void* d_ws, size_t ws_size,
                              hipStream_t stream)
{
    char* ws = (char*)d_ws;
    auto align256 = [](size_t v) { return (v + 255) & ~(size_t)255; };

    size_t off = 0;
    size_t off_flag = off;            off = align256(off + 4);
    size_t p_off[26];
    for (int i = 0; i < 26; ++i) { p_off[i] = off; off = align256(off + (size_t)in_sizes[i] * 2); }
    size_t off_mb   = off; off = align256(off + (size_t)8 * Nn * 4);
    size_t off_q    = off; off = align256(off + (size_t)Bn * Nn * 256 * 2);
    size_t off_k    = off; off = align256(off + (size_t)Bn * Nn * 256 * 2);
    size_t off_v    = off; off = align256(off + (size_t)Bn * Nn * DHn * 2);
    size_t off_vt   = off; off = align256(off + (size_t)Bn * Nn * DHn * 2);
    size_t off_o    = off; off = align256(off + (size_t)Bn * Nn * DHn * 2);
    size_t off_xt   = off; off = align256(off + (size_t)Bn * Nn * CIN * 2);
    size_t off_wqkv = off; off = align256(off + (size_t)1536 * CIN * 2);
    size_t off_al   = off; off = align256(off + (size_t)1536 * 4);
    size_t off_be   = off; off = align256(off + (size_t)1536 * 4);
    size_t base = off;

    const size_t attn_per_b = (size_t)8 * Nn * Nn * 2;
    int GB = 0;
    const int cand[4] = {8, 4, 2, 1};
    for (int ci = 0; ci < 4; ++ci) {
        if (base + (size_t)cand[ci] * attn_per_b + 512 <= ws_size) { GB = cand[ci]; break; }
    }
    if (!GB) return; // ws too small -> zeros out (diagnostic absmax ~17.4)

    size_t off_attn = base;

    int*  flag = (int*)(ws + off_flag);
    bf16* Pb[26];
    for (int i = 0; i < 26; ++i) Pb[i] = (bf16*)(ws + p_off[i]);
    float* mb   = (float*)(ws + off_mb);
    bf16* qbuf  = (bf16*)(ws + off_q);
    bf16* kbuf  = (bf16*)(ws + off_k);
    bf16* vbuf  = (bf16*)(ws + off_v);
    bf16* vt    = (bf16*)(ws + off_vt);
    bf16* obuf  = (bf16*)(ws + off_o);
    bf16* xt    = (bf16*)(ws + off_xt);
    bf16* wqkv  = (bf16*)(ws + off_wqkv);
    float* alf  = (float*)(ws + off_al);
    float* bef  = (float*)(ws + off_be);
    bf16* attn  = (bf16*)(ws + off_attn);
    const int* idxs = (const int*)d_in[26];

    k_detect<<<1, 64, 0, stream>>>((const unsigned*)d_in[0], flag);

    ConvArgs ca;
    for (int i = 0; i < 26; ++i) { ca.src[i] = d_in[i]; ca.dstoff[i] = p_off[i]; ca.n[i] = in_sizes[i]; }
    k_convb_all<<<dim3(600, 26), 256, 0, stream>>>(ca, ws, flag);

    bf16 *x = Pb[0], *Wq = Pb[1], *bq = Pb[2], *qs = Pb[3], *qb = Pb[4],
         *Wk = Pb[5], *bk = Pb[6], *ks = Pb[7], *kb = Pb[8],
         *Wv = Pb[9], *bv = Pb[10], *vs = Pb[11], *vb = Pb[12],
         *Wvl = Pb[13], *bvl = Pb[14], *vls = Pb[15], *vlb = Pb[16],
         *W1 = Pb[17], *b1 = Pb[18], *W2 = Pb[19], *b2v = Pb[20],
         *Wp = Pb[21], *bp = Pb[22], *ps = Pb[23], *pb = Pb[24], *ab = Pb[25];

    k_wpack<<<dim3((1536 * 48 + 255) / 256), 256, 0, stream>>>(Wq, Wk, Wv, wqkv);
    k_affine<<<dim3(6), 256, 0, stream>>>(bq, qs, qb, bk, ks, kb, bv, vs, vb, alf, bef);
    k_mixbias<<<dim3((8 * Nn + 255) / 256), 256, 0, stream>>>(ab, W1, b1, mb);
    k_xt<<<dim3(25, 12, 8), 256, 0, stream>>>(x, xt);

    k_proj_m<<<dim3(13, 24, 8), 256, 0, stream>>>(xt, wqkv, alf, bef, qbuf, kbuf, vbuf);
    k_vt<<<dim3(25, 32, 8), 256, 0, stream>>>(vbuf, vt);

    for (int bi0 = 0; bi0 < Bn; bi0 += GB) {
        k_logits_m<<<dim3(13, 13, GB * 8), 256, 0, stream>>>(qbuf, kbuf, W1, mb, idxs, attn, bi0);
        k_softmax_mix<<<dim3(Nn, GB), 256, 0, stream>>>(attn, W2, b2v);
        k_pv_m<<<dim3(2, 13, GB * 8), 256, 0, stream>>>(attn, vt, obuf, bi0);
    }

    k_dwconv_add<<<dim3(1, Nn / 2, 8), 256, 0, stream>>>(vbuf, Wvl, bvl, vls, vlb, obuf);
    k_outproj_m<<<dim3(13, 6, 8), 256, 0, stream>>>(Wp, obuf, bp, ps, pb, d_out, flag);
}